// Round 7
// baseline (212.954 us; speedup 1.0000x reference)
//
#include <hip/hip_runtime.h>
#include <math.h>

#define NB 128
#define NT 512
#define NEDIM 128
#define NNEG 64
#define SCHUNK 16
#define CPB 2                     // chunks per block; B staged once per pair
#define SBLK (SCHUNK * CPB)       // 32 s-rows per block
#define NXBLK (NT / SBLK)         // 16 x-blocks per batch row
#define NBLKS (NB * NXBLK)        // 2048 blocks
#define WSN (NBLKS * 4)           // 8192 per-wave partials

typedef __bf16 bf16x8 __attribute__((ext_vector_type(8)));
typedef float  f32x4  __attribute__((ext_vector_type(4)));

__device__ __forceinline__ bf16x8 pack8(float4 v0, float4 v1) {
    bf16x8 o;
    o[0] = (__bf16)v0.x; o[1] = (__bf16)v0.y; o[2] = (__bf16)v0.z; o[3] = (__bf16)v0.w;
    o[4] = (__bf16)v1.x; o[5] = (__bf16)v1.y; o[6] = (__bf16)v1.z; o[7] = (__bf16)v1.w;
    return o;
}

__device__ __forceinline__ float chunk_const(int s0c) {
    const float wgt[4] = {1.f/261632.f, 1.f/261120.f, 1.f/260608.f, 1.f/260096.f};
    const float LOG65 = 4.1743873f;
    float c = 0.f;
    #pragma unroll
    for (int i = 1; i <= 4; ++i) {
        int hi = min(SCHUNK, (NT - i) - s0c);
        if (hi > 0) c += (float)hi * LOG65 * wgt[i - 1];
    }
    return c;
}

// MFMA + epilogue for one 16-row chunk; returns this thread's loss partial.
// Fragment layouts identical to the verified R1 kernel (absmax 0).
__device__ __forceinline__ float compute_chunk(
    const __bf16* __restrict__ Af, const __bf16* __restrict__ Bf,
    const __bf16* __restrict__ Pf,
    int s0c, int L, int lane, int w, int q, int fl)
{
    const float LOG65 = 4.1743873f;
    const float wgt[4] = {1.f/261632.f, 1.f/261120.f, 1.f/260608.f, 1.f/260096.f};

    f32x4 acc[6];
    #pragma unroll
    for (int nt = 0; nt < 6; ++nt) acc[nt] = (f32x4){0.f, 0.f, 0.f, 0.f};

    __builtin_amdgcn_s_setprio(1);        // T5: blocks on a CU are phase-staggered
    #pragma unroll
    for (int kstep = 0; kstep < 4; ++kstep) {
        int CsA = kstep * 4 + w;
        bf16x8 af = *(const bf16x8*)(&Af[(size_t)(((CsA * 64 + lane) ^ (CsA & 7))) * 8]);
        int ebB = kstep * 4 + q;
        int xb  = ebB & 7;
        bf16x8 bv[6];
        #pragma unroll
        for (int nt = 0; nt < 4; ++nt)
            bv[nt] = *(const bf16x8*)(&Bf[(size_t)(((ebB * 64 + nt * 16 + fl) ^ xb)) * 8]);
        #pragma unroll
        for (int t = 0; t < 2; ++t)
            bv[4 + t] = *(const bf16x8*)(&Pf[(size_t)(((ebB * 32 + t * 16 + fl) ^ xb)) * 8]);
        #pragma unroll
        for (int nt = 0; nt < 6; ++nt)
            acc[nt] = __builtin_amdgcn_mfma_f32_16x16x32_bf16(af, bv[nt], acc[nt], 0, 0, 0);
    }
    __builtin_amdgcn_s_setprio(0);

    const int sloc = w * 4 + q;
    const int sg   = s0c + sloc;
    float lossacc = 0.f;
    #pragma unroll
    for (int r = 0; r < 4; ++r) {
        int ip   = r + 1;
        int pcol = sloc + r;                              // in [0,19)
        float z0 = acc[0][r], z1 = acc[1][r];
        float z2 = acc[2][r], z3 = acc[3][r];
        float pv = (pcol < 16) ? acc[4][r] : acc[5][r];   // both names static
        float p  = __shfl(pv, (lane & 48) | (pcol & 15));
        float mx = fmaxf(fmaxf(z0, z1), fmaxf(z2, z3));
        mx = fmaxf(mx, __shfl_xor(mx, 1));
        mx = fmaxf(mx, __shfl_xor(mx, 2));
        mx = fmaxf(mx, __shfl_xor(mx, 4));
        mx = fmaxf(mx, __shfl_xor(mx, 8));
        mx = fmaxf(mx, p);
        float es = __expf(z0 - mx) + __expf(z1 - mx)
                 + __expf(z2 - mx) + __expf(z3 - mx);
        es += __shfl_xor(es, 1);
        es += __shfl_xor(es, 2);
        es += __shfl_xor(es, 4);
        es += __shfl_xor(es, 8);
        es += __expf(p - mx);
        float loss = __logf(es) + (mx - p);
        loss = (sg < L) ? loss : LOG65;
        bool take = (sg < NT - ip) && (fl == 0);
        lossacc += take ? wgt[r] * loss : 0.f;
    }
    return lossacc;
}

// R6 geometry (40 KiB LDS, 4 blocks/CU, CPB=2) + issue-order fix:
// sample_ids loaded coalesced (lane<->n) + shfl-distributed; A-loads issued
// FIRST so the B-gather's dependent wait overlaps them; all global loads in
// flight before any convert/LDS-write.  setprio(1) around the MFMA loop.
__launch_bounds__(256, 4)
__global__ void cpc_mfma_kernel(const float* __restrict__ base,        // (B,T,E)
                                const float* __restrict__ mce,         // (B,T,E,K)
                                const int*  __restrict__ seq_lens,     // (B)
                                const int*  __restrict__ sample_ids,   // (B,NNEG)
                                float* __restrict__ ws)                // (WSN)
{
    const int b    = blockIdx.y;
    const int s0   = blockIdx.x * SBLK;
    const int slot = (b * NXBLK + blockIdx.x) * 4;
    const int L    = seq_lens[b];

    // Whole block masked: analytic result for both chunks.
    if (s0 >= L) {
        if (threadIdx.x < 4) {
            float c = (threadIdx.x == 0)
                    ? chunk_const(s0) + chunk_const(s0 + SCHUNK) : 0.f;
            ws[slot + threadIdx.x] = c;
        }
        return;
    }

    __shared__ __align__(16) __bf16 Afrag[1024 * 8];   // 16 KiB, xor ^(Cs&7)
    __shared__ __align__(16) __bf16 Bfrag[1024 * 8];   // 16 KiB, xor ^(eb&7)
    __shared__ __align__(16) __bf16 Pfrag[512 * 8];    //  8 KiB, xor ^(eb&7)

    const int tid  = threadIdx.x;
    const int lane = tid & 63;
    const int w    = tid >> 6;
    const int q    = lane >> 4;
    const int fl   = lane & 15;

    const float4* mce4  = (const float4*)mce;
    const float4* base4 = (const float4*)base;

    // ---- (1) coalesced sample_ids: lane <-> n, one dword per lane ----
    const int rr = sample_ids[b * NNEG + lane];

    // ---- per-thread A staging geometry ----
    const int sA  = tid & 15;             // row within chunk
    const int ebA = tid >> 4;             // e-block of 8
    const int CsS = (ebA >> 2) * 4 + (sA >> 2);
    const int bcA = CsS * 64 + (ebA & 3) * 16 + (sA & 3) * 4;
    const int xA  = CsS & 7;
    const float4* srcA = mce4 + (size_t)(b * NT + s0 + sA) * NEDIM + ebA * 8;

    // ---- (2) issue A(c0) loads FIRST (independent of sample_ids) ----
    float4 va[8];
    #pragma unroll
    for (int u = 0; u < 8; ++u) va[u] = srcA[u];

    // ---- issue B loads (waits only on rr; A already in flight) ----
    float4 vb0[4], vb1[4];
    #pragma unroll
    for (int it = 0; it < 4; ++it) {
        int n = (tid >> 4) + 16 * it;     // (tid+256*it)>>4
        int r = __shfl(rr, n);
        const float4* srcb = base4 + (size_t)r * (NEDIM / 4) + (tid & 15) * 2;
        vb0[it] = srcb[0]; vb1[it] = srcb[1];
    }

    // ---- write A(c0): transpose k->row, f32->bf16 ----
    {
        const float* vf = (const float*)va;
        #pragma unroll
        for (int k = 0; k < 4; ++k) {
            bf16x8 o;
            #pragma unroll
            for (int u = 0; u < 8; ++u) o[u] = (__bf16)vf[4 * u + k];
            *(bf16x8*)(&Afrag[(size_t)((bcA + k) ^ xA) * 8]) = o;
        }
    }

    // ---- issue P(c0) loads, then write B, then write P ----
    float4 vp0[2], vp1[2];
    #pragma unroll
    for (int it = 0; it < 2; ++it) {
        int j = (tid >> 4) + 16 * it;
        int srow = s0 + 1 + j; if (srow > NT - 1) srow = NT - 1;
        const float4* srcp = base4 + (size_t)(b * NT + srow) * (NEDIM / 4) + (tid & 15) * 2;
        vp0[it] = srcp[0]; vp1[it] = srcp[1];
    }
    #pragma unroll
    for (int it = 0; it < 4; ++it) {
        int n  = (tid >> 4) + 16 * it;
        int eb = tid & 15;
        *(bf16x8*)(&Bfrag[(size_t)((eb * 64 + n) ^ (eb & 7)) * 8]) = pack8(vb0[it], vb1[it]);
    }
    #pragma unroll
    for (int it = 0; it < 2; ++it) {
        int j   = (tid >> 4) + 16 * it;
        int ebP = tid & 15;
        *(bf16x8*)(&Pfrag[(size_t)((ebP * 32 + j) ^ (ebP & 7)) * 8]) = pack8(vp0[it], vp1[it]);
    }
    __syncthreads();

    const int  s1 = s0 + SCHUNK;
    const bool v1 = (s1 < L);

    // ---- T14: issue chunk-1 A loads EARLY (HBM latency hides under c0) ----
    float4 av[8];
    if (v1) {
        const float4* src = srcA + (size_t)SCHUNK * NEDIM;
        #pragma unroll
        for (int u = 0; u < 8; ++u) av[u] = src[u];
    }

    float lossacc = compute_chunk(Afrag, Bfrag, Pfrag, s0, L, lane, w, q, fl);

    if (v1) {
        __syncthreads();                  // all reads of A(c0)/P(c0) done
        {
            const float* vf = (const float*)av;
            #pragma unroll
            for (int k = 0; k < 4; ++k) {
                bf16x8 o;
                #pragma unroll
                for (int u = 0; u < 8; ++u) o[u] = (__bf16)vf[4 * u + k];
                *(bf16x8*)(&Afrag[(size_t)((bcA + k) ^ xA) * 8]) = o;
            }
        }
        #pragma unroll
        for (int it = 0; it < 2; ++it) {  // restage P for c1 (rows L2-hot)
            int j = (tid >> 4) + 16 * it;
            int ebP = tid & 15;
            int srow = s1 + 1 + j; if (srow > NT - 1) srow = NT - 1;
            const float4* srcp = base4 + (size_t)(b * NT + srow) * (NEDIM / 4) + ebP * 2;
            *(bf16x8*)(&Pfrag[(size_t)((ebP * 32 + j) ^ (ebP & 7)) * 8]) = pack8(srcp[0], srcp[1]);
        }
        __syncthreads();
        lossacc += compute_chunk(Afrag, Bfrag, Pfrag, s1, L, lane, w, q, fl);
    } else if (tid == 0) {
        lossacc += chunk_const(s1);       // chunk 1 fully masked
    }

    lossacc += __shfl_xor(lossacc, 16);
    lossacc += __shfl_xor(lossacc, 32);
    if (lane == 0) ws[slot + w] = lossacc;
}

// Sum the 8192 per-wave partials -> out[0]. One block, no atomics.
__global__ void reduce_k(const float* __restrict__ ws, float* __restrict__ out) {
    const int tid = threadIdx.x;   // 256
    float s = 0.f;
    #pragma unroll
    for (int i = 0; i < WSN / 256; ++i) s += ws[tid + 256 * i];
    s += __shfl_xor(s, 1);
    s += __shfl_xor(s, 2);
    s += __shfl_xor(s, 4);
    s += __shfl_xor(s, 8);
    s += __shfl_xor(s, 16);
    s += __shfl_xor(s, 32);
    __shared__ float wsum[4];
    if ((tid & 63) == 0) wsum[tid >> 6] = s;
    __syncthreads();
    if (tid == 0) out[0] = wsum[0] + wsum[1] + wsum[2] + wsum[3];
}

extern "C" void kernel_launch(void* const* d_in, const int* in_sizes, int n_in,
                              void* d_out, int out_size, void* d_ws, size_t ws_size,
                              hipStream_t stream) {
    (void)in_sizes; (void)n_in; (void)out_size; (void)ws_size;
    const float* base       = (const float*)d_in[0];
    const float* mce        = (const float*)d_in[1];
    const int*   seq_lens   = (const int*)d_in[2];
    const int*   sample_ids = (const int*)d_in[3];
    float* out = (float*)d_out;
    float* ws  = (float*)d_ws;   // 8192 floats; every wave writes its slot

    dim3 grid(NXBLK, NB);
    cpc_mfma_kernel<<<grid, 256, 0, stream>>>(base, mce, seq_lens, sample_ids, ws);
    reduce_k<<<1, 256, 0, stream>>>(ws, out);
}